// Round 5
// baseline (143.609 us; speedup 1.0000x reference)
//
#include <hip/hip_runtime.h>
#include <stdint.h>

#define N_TOTAL (8 * 128 * 128 * 128)   // 16,777,216 elements
#define THREADS 256
#define TILE    4096                    // elements per block per input array
#define BLOCKS  (N_TOTAL / TILE)        // 4096, exact
#define FINAL_THREADS 1024

__device__ __forceinline__ float svl_elem(float x, float t) {
    // BCEWithLogits (stable): max(x,0) - x*t + log1p(exp(-|x|))
    float loss = fmaxf(x, 0.0f) - x * t + __logf(1.0f + __expf(-fabsf(x)));
    // sigmoid(x) > 0.5  <=>  x > 0 ; weight = (pred XOR tgt) ? 1.5 : 1.0
    bool pred = x > 0.0f;
    bool tgt  = t > 0.5f;
    float w = (pred != tgt) ? 1.5f : 1.0f;
    return loss * w;
}

__global__ __launch_bounds__(THREADS) void svl_partial_kernel(
        const float* __restrict__ yp, const float* __restrict__ yt,
        float* __restrict__ partial) {
    __shared__ float bp[TILE];   // 16 KB
    __shared__ float bt[TILE];   // 16 KB  -> 32 KB total, 5 blocks/CU

    const int lane = threadIdx.x & 63;
    const int wave = threadIdx.x >> 6;
    const size_t base = (size_t)blockIdx.x * TILE;

    // Stage 16 KB per array via global_load_lds DMA (16 B per lane per instr;
    // LDS dest = wave-uniform base + lane*16). Each wave stages 4 contiguous
    // 1 KB chunks per array -> 8 outstanding DMA ops per thread.
    #pragma unroll
    for (int c = 0; c < 4; ++c) {
        const int chunk = wave * 4 + c;           // 0..15, wave-uniform
        const int off = chunk * 256 + lane * 4;   // element offset in tile
        __builtin_amdgcn_global_load_lds(
            (const __attribute__((address_space(1))) uint32_t*)(yp + base + off),
            (__attribute__((address_space(3))) uint32_t*)(bp + chunk * 256),
            16, 0, 0);
        __builtin_amdgcn_global_load_lds(
            (const __attribute__((address_space(1))) uint32_t*)(yt + base + off),
            (__attribute__((address_space(3))) uint32_t*)(bt + chunk * 256),
            16, 0, 0);
    }
    __syncthreads();   // compiler emits s_waitcnt vmcnt(0) before s_barrier

    float acc = 0.0f;
    #pragma unroll
    for (int k = 0; k < TILE / THREADS; ++k) {    // 16 elements/thread
        int e = threadIdx.x + k * THREADS;        // stride-256: 2 lanes/bank, free
        acc += svl_elem(bp[e], bt[e]);
    }

    // wave-64 shuffle reduction
    #pragma unroll
    for (int off = 32; off > 0; off >>= 1)
        acc += __shfl_down(acc, off, 64);

    __syncthreads();                  // done reading bp; reuse it for wave sums
    if (lane == 0) bp[wave] = acc;
    __syncthreads();

    if (threadIdx.x == 0) {
        float s = 0.0f;
        #pragma unroll
        for (int w = 0; w < THREADS / 64; ++w) s += bp[w];
        partial[blockIdx.x] = s;
    }
}

__global__ __launch_bounds__(FINAL_THREADS) void svl_final_kernel(
        const float* __restrict__ partial, float* __restrict__ out) {
    float acc = 0.0f;
    #pragma unroll
    for (int i = threadIdx.x; i < BLOCKS; i += FINAL_THREADS)
        acc += partial[i];

    #pragma unroll
    for (int off = 32; off > 0; off >>= 1)
        acc += __shfl_down(acc, off, 64);

    __shared__ float smem[FINAL_THREADS / 64];
    int lane = threadIdx.x & 63;
    int wave = threadIdx.x >> 6;
    if (lane == 0) smem[wave] = acc;
    __syncthreads();

    if (threadIdx.x == 0) {
        float s = 0.0f;
        #pragma unroll
        for (int w = 0; w < FINAL_THREADS / 64; ++w) s += smem[w];
        out[0] = s * (1.0f / (float)N_TOTAL);
    }
}

extern "C" void kernel_launch(void* const* d_in, const int* in_sizes, int n_in,
                              void* d_out, int out_size, void* d_ws, size_t ws_size,
                              hipStream_t stream) {
    const float* yp = (const float*)d_in[0];
    const float* yt = (const float*)d_in[1];
    float* out = (float*)d_out;
    float* partial = (float*)d_ws;   // BLOCKS floats = 16 KiB scratch

    svl_partial_kernel<<<BLOCKS, THREADS, 0, stream>>>(yp, yt, partial);
    svl_final_kernel<<<1, FINAL_THREADS, 0, stream>>>(partial, out);
}